// Round 8
// baseline (126.698 us; speedup 1.0000x reference)
//
#include <hip/hip_runtime.h>
#include <math.h>

// Second-order IIR (B=1024 rows, T=16384), fp32.
// V9: register-resident micro-chunk design — no LDS staging of u or y.
// Each thread holds 8 float4 micro-chunks (m = tid + 512k) from coalesced
// loads; pass 1 computes the 4-step zero-state response per micro-chunk
// directly in registers (u-history via __shfl_up; 8 lane-0 threads use
// tiny global float2 loads). LDS holds ONLY scan state (36 KB):
//   level 1: every thread folds 8 adjacent microstates with A^4 -> 512
//            chunk states;  level 2: wave-0 affine Kogge-Stone (V8-verified,
//            M=A^32, W=A^256);  level 3: every thread walks chunk prefix
//            back down to 8 micro-prefixes.
// Pass 3 replays 4 exact steps per micro-chunk and stores float4 straight
// from registers, coalesced. No barrier between load and pass 1: compiler
// per-use waitcnt overlaps the HBM burst with compute (the lockstep-phase
// bubble V7/V8 paid). Zero inline asm (V7 lesson).

#define TLEN  16384
#define NT    512
#define NK    8                       // float4 micro-chunks per thread
#define CD2   4096                    // chunk-state float2 base (512 entries)
#define LDS_FLOATS 9216               // 4096*2 (microstates) + 512*2 = 36864 B

// float2-slot swizzle for the microstate buffer: keeps the fold-8 reads
// (slot 8t+i) ~2-way instead of 16-way; write/read patterns both swizzled.
__device__ __forceinline__ int s2(int x) { return x ^ ((x >> 3) & 7); }

__device__ __forceinline__ void mat2_sq(float& m00, float& m01, float& m10, float& m11) {
    float t00 = m00*m00 + m01*m10;
    float t01 = m00*m01 + m01*m11;
    float t10 = m10*m00 + m11*m10;
    float t11 = m10*m01 + m11*m11;
    m00 = t00; m01 = t01; m10 = t10; m11 = t11;
}

__global__ __launch_bounds__(NT, 4)
void iir_kernel(const float* __restrict__ bc,
                const float* __restrict__ rho_p,
                const float* __restrict__ psi_p,
                const float* __restrict__ u_in,
                const float* __restrict__ y_init,
                const float* __restrict__ u_init,
                float* __restrict__ y_out)
{
    __shared__ float lds[LDS_FLOATS];
    float2* ms = (float2*)lds;          // microstates / micro-prefixes (4096)
    float2* cd = ((float2*)lds) + CD2;  // chunk states / prefixes (512)
    const int row  = blockIdx.x;
    const int tid  = threadIdx.x;
    const int lane = tid & 63;

    const float*  urow = u_in  + (size_t)row * TLEN;
    float*        orow = y_out + (size_t)row * TLEN;
    const float4* up4  = (const float4*)urow;

    // ---- coalesced register loads (overlap everything below) ----
    float4 uv[NK];
    #pragma unroll
    for (int k = 0; k < NK; ++k) uv[k] = up4[tid + 512*k];

    // ---- u-history per micro-chunk: (u[4m-2], u[4m-1]) ----
    float2 ui = *(const float2*)&u_init[2*row];   // (u_-1, u_-2)
    float2 hist[NK];
    if (lane == 0) {                              // 8 threads/block: tiny loads
        #pragma unroll
        for (int k = 0; k < NK; ++k) {
            int m = tid + 512*k;
            if (m > 0) hist[k] = *(const float2*)(urow + 4*m - 2);
        }
    }
    if (tid == 0) hist[0] = make_float2(ui.y, ui.x);  // (u_-2, u_-1)

    // scalar params (overlap load latency)
    const float rho = rho_p[0];
    const float psi = psi_p[0];
    const float r   = 1.0f / (1.0f + expf(-rho));
    const float th  = 3.14159265358979323846f / (1.0f + expf(-psi));
    const float a1  = -2.0f * r * cosf(th);
    const float a2  = r * r;
    const float b0  = bc[0], b1 = bc[1], b2 = bc[2];

    #pragma unroll
    for (int k = 0; k < NK; ++k) {                // lanes 1..63: history via shfl
        float pz = __shfl_up(uv[k].z, 1);
        float pw = __shfl_up(uv[k].w, 1);
        if (lane != 0) hist[k] = make_float2(pz, pw);
    }

    // ---- pass 1: zero-state 4-step micro response -> (y3, y2) ----
    #pragma unroll
    for (int k = 0; k < NK; ++k) {
        float m2 = hist[k].x, m1 = hist[k].y;
        float4 u4 = uv[k];
        float va = fmaf(b2, m2,   fmaf(b1, m1,   b0*u4.x));
        float ya = va;                                       // y-1=y-2=0
        float vb = fmaf(b2, m1,   fmaf(b1, u4.x, b0*u4.y));
        float yb = fmaf(-a1, ya, vb);
        float vc = fmaf(b2, u4.x, fmaf(b1, u4.y, b0*u4.z));
        float yc = fmaf(-a1, yb, fmaf(-a2, ya, vc));
        float vd = fmaf(b2, u4.y, fmaf(b1, u4.z, b0*u4.w));
        float yd = fmaf(-a1, yc, fmaf(-a2, yb, vd));
        ms[s2(tid + 512*k)] = make_float2(yd, yc);
    }
    __syncthreads();                               // microstates visible

    // A^4 (micro-chunk step matrix)
    float q00 = -a1, q01 = -a2, q10 = 1.0f, q11 = 0.0f;
    mat2_sq(q00, q01, q10, q11);
    mat2_sq(q00, q01, q10, q11);

    // ---- level 1: fold 8 adjacent microstates -> chunk state (32 elems) ----
    {
        float s0 = 0.0f, s1 = 0.0f;
        #pragma unroll
        for (int i = 0; i < 8; ++i) {
            float2 d = ms[s2(8*tid + i)];
            float n0 = fmaf(q00, s0, fmaf(q01, s1, d.x));
            float n1 = fmaf(q10, s0, fmaf(q11, s1, d.y));
            s0 = n0; s1 = n1;
        }
        cd[tid] = make_float2(s0, s1);
    }
    __syncthreads();                               // chunk states visible

    // ---- level 2: wave-0 affine scan over 512 chunk states (V8-verified) ----
    if (tid < 64) {
        const int l = tid;
        float m00 = q00, m01 = q01, m10 = q10, m11 = q11;
        mat2_sq(m00, m01, m10, m11);
        mat2_sq(m00, m01, m10, m11);
        mat2_sq(m00, m01, m10, m11);               // M = A^32

        float da[8], db[8];
        #pragma unroll
        for (int j = 0; j < 8; ++j) { float2 d = cd[8*l + j]; da[j] = d.x; db[j] = d.y; }

        float seed0 = 0.0f, seed1 = 0.0f;
        if (l == 0) { seed0 = y_init[2*row]; seed1 = y_init[2*row + 1]; }

        float s0 = seed0, s1 = seed1;              // serial fold of 8 chunks
        #pragma unroll
        for (int m = 0; m < 8; ++m) {
            float n0 = fmaf(m00, s0, fmaf(m01, s1, da[m]));
            float n1 = fmaf(m10, s0, fmaf(m11, s1, db[m]));
            s0 = n0; s1 = n1;
        }
        float w00 = m00, w01 = m01, w10 = m10, w11 = m11;
        mat2_sq(w00, w01, w10, w11);
        mat2_sq(w00, w01, w10, w11);
        mat2_sq(w00, w01, w10, w11);               // W = M^8 = A^256
        #pragma unroll
        for (int p = 0; p < 6; ++p) {              // Kogge-Stone over 64 lanes
            float o0 = __shfl_up(s0, 1 << p);
            float o1 = __shfl_up(s1, 1 << p);
            if (l >= (1 << p)) {
                s0 = fmaf(w00, o0, fmaf(w01, o1, s0));
                s1 = fmaf(w10, o0, fmaf(w11, o1, s1));
            }
            if (p < 5) mat2_sq(w00, w01, w10, w11);
        }
        float p0 = __shfl_up(s0, 1);               // incoming for chunk 8l
        float p1 = __shfl_up(s1, 1);
        if (l == 0) { p0 = seed0; p1 = seed1; }
        float c0 = p0, c1 = p1;
        #pragma unroll
        for (int m = 0; m < 8; ++m) {
            cd[8*l + m] = make_float2(c0, c1);     // incoming state per chunk
            float n0 = fmaf(m00, c0, fmaf(m01, c1, da[m]));
            float n1 = fmaf(m10, c0, fmaf(m11, c1, db[m]));
            c0 = n0; c1 = n1;
        }
    }
    __syncthreads();                               // chunk prefixes visible

    // ---- level 3: walk chunk prefix down to 8 micro-prefixes (in place) ----
    {
        float2 P = cd[tid];
        float p0 = P.x, p1 = P.y;
        #pragma unroll
        for (int i = 0; i < 8; ++i) {
            int s = s2(8*tid + i);
            float2 d = ms[s];                      // read d before overwrite
            ms[s] = make_float2(p0, p1);           // micro-prefix (y_{4m-1}, y_{4m-2})
            float n0 = fmaf(q00, p0, fmaf(q01, p1, d.x));
            float n1 = fmaf(q10, p0, fmaf(q11, p1, d.y));
            p0 = n0; p1 = n1;
        }
    }
    __syncthreads();                               // micro-prefixes visible

    // ---- pass 3: 4 exact steps per micro-chunk, coalesced store from regs ----
    float4* op4 = (float4*)orow;
    #pragma unroll
    for (int k = 0; k < NK; ++k) {
        float2 pin = ms[s2(tid + 512*k)];          // (y_{4m-1}, y_{4m-2})
        float m2 = hist[k].x, m1 = hist[k].y;
        float4 u4 = uv[k];
        float va = fmaf(b2, m2,   fmaf(b1, m1,   b0*u4.x));
        float ya = fmaf(-a1, pin.x, fmaf(-a2, pin.y, va));
        float vb = fmaf(b2, m1,   fmaf(b1, u4.x, b0*u4.y));
        float yb = fmaf(-a1, ya,    fmaf(-a2, pin.x, vb));
        float vc = fmaf(b2, u4.x, fmaf(b1, u4.y, b0*u4.z));
        float yc = fmaf(-a1, yb,    fmaf(-a2, ya,  vc));
        float vd = fmaf(b2, u4.y, fmaf(b1, u4.z, b0*u4.w));
        float yd = fmaf(-a1, yc,    fmaf(-a2, yb,  vd));
        float4 w; w.x = ya; w.y = yb; w.z = yc; w.w = yd;
        op4[tid + 512*k] = w;
    }
}

extern "C" void kernel_launch(void* const* d_in, const int* in_sizes, int n_in,
                              void* d_out, int out_size, void* d_ws, size_t ws_size,
                              hipStream_t stream) {
    const float* bc    = (const float*)d_in[0];
    const float* rho   = (const float*)d_in[1];
    const float* psi   = (const float*)d_in[2];
    const float* u_in  = (const float*)d_in[3];
    const float* y_in  = (const float*)d_in[4];
    const float* u_ini = (const float*)d_in[5];
    float* y = (float*)d_out;
    const int B = in_sizes[3] / TLEN;     // 1024
    iir_kernel<<<B, NT, 0, stream>>>(bc, rho, psi, u_in, y_in, u_ini, y);
}